// Round 1
// baseline (2885.867 us; speedup 1.0000x reference)
//
#include <hip/hip_runtime.h>

// FusedMoEIntegrator — MI355X/gfx950
// T=16384 tokens, D=1024, E=8 experts top-2, 2 iterations, H=64, CTX=2048.
// Strategy: bf16 MFMA (16x16x32) for all matmuls; weights pre-transposed to
// [N][K] bf16 once per launch; expert (2048->64->3072) fused into one kernel
// with the _inl epilogue (ctrl never materialized); routed slots grouped by
// expert via atomic bucketing; fp32 atomics combine routed contributions.
// Workspace need: ~227 MB.

#define TOK   16384
#define DDIM  1024
#define NEXP  8
#define DTC   0.1f

using f32x4 = __attribute__((ext_vector_type(4))) float;
using bfv8  = __attribute__((ext_vector_type(8))) short;

__device__ __forceinline__ unsigned short f2bf(float x){
  unsigned u = __builtin_bit_cast(unsigned, x);
  u += 0x7fffu + ((u >> 16) & 1u);          // RNE (finite inputs only)
  return (unsigned short)(u >> 16);
}
__device__ __forceinline__ float bf2f(unsigned short h){
  return __builtin_bit_cast(float, ((unsigned)h) << 16);
}
__device__ __forceinline__ float geluf(float x){
  return 0.5f * x * (1.0f + erff(x * 0.7071067811865476f));   // exact gelu
}
__device__ __forceinline__ float sigmf(float x){ return 1.0f/(1.0f+expf(-x)); }
__device__ __forceinline__ float softpf(float x){
  return x > 0.0f ? x + log1pf(expf(-x)) : log1pf(expf(x));
}
__device__ __forceinline__ f32x4 mfma16(bfv8 a, bfv8 b, f32x4 c){
  return __builtin_amdgcn_mfma_f32_16x16x32_bf16(a, b, c, 0, 0, 0);
}

// -------- transpose+cast: src f32 [R][C] (batch z) -> dst bf16 [C][R] --------
__global__ __launch_bounds__(256) void transpose_cast(
    const float* __restrict__ src, unsigned short* __restrict__ dst, int R, int C)
{
  __shared__ float tile[32][33];
  size_t bo = (size_t)blockIdx.z * R * C;
  const float* s = src + bo;
  unsigned short* d = dst + bo;
  int c0 = blockIdx.x * 32, r0 = blockIdx.y * 32;
  int tx = threadIdx.x, ty = threadIdx.y;
  #pragma unroll
  for (int j = 0; j < 4; j++)
    tile[ty + 8*j][tx] = s[(size_t)(r0 + ty + 8*j) * C + c0 + tx];
  __syncthreads();
  #pragma unroll
  for (int j = 0; j < 4; j++)
    d[(size_t)(c0 + ty + 8*j) * R + r0 + tx] = f2bf(tile[tx][ty + 8*j]);
}

// -------- main GEMM: C[M,N] = A[M,K] @ BT[N,K]^T, 128x128 tile, 4 waves ------
// EPI 0: out_bf16 = bf16(gelu(acc + bias[col]))
// EPI 1: integ[row*1024+col] += halt[row] * (acc + bias[col]) * iw[col]
template<int EPI, bool AF32>
__global__ __launch_bounds__(256) void gemm_k(
    const void* __restrict__ Ap, const unsigned short* __restrict__ BT,
    const float* __restrict__ bias, int Kd, int N,
    unsigned short* __restrict__ obf,
    const float* __restrict__ halt, const float* __restrict__ iw,
    float* __restrict__ integ)
{
  __shared__ unsigned short As[128][72];
  __shared__ unsigned short Bs[128][72];
  const int tid  = threadIdx.x;
  const int lane = tid & 63;
  const int w    = tid >> 6;
  const int wm   = w >> 1, wn = w & 1;
  const int gm0  = blockIdx.y * 128, gn0 = blockIdx.x * 128;
  const int srow  = tid >> 1;          // 0..127
  const int shalf = (tid & 1) * 32;    // k offset within 64

  f32x4 acc[4][4];
  #pragma unroll
  for (int i = 0; i < 4; i++)
    #pragma unroll
    for (int j = 0; j < 4; j++)
      acc[i][j] = f32x4{0.f, 0.f, 0.f, 0.f};

  for (int k0 = 0; k0 < Kd; k0 += 64) {
    if (AF32) {
      const float* A = (const float*)Ap + (size_t)(gm0 + srow) * Kd + k0 + shalf;
      unsigned short tmp[32];
      #pragma unroll
      for (int q = 0; q < 8; q++) {
        float4 f = *(const float4*)(A + q * 4);
        tmp[q*4+0] = f2bf(f.x); tmp[q*4+1] = f2bf(f.y);
        tmp[q*4+2] = f2bf(f.z); tmp[q*4+3] = f2bf(f.w);
      }
      #pragma unroll
      for (int q = 0; q < 4; q++)
        *(uint4*)&As[srow][shalf + q*8] = *(uint4*)&tmp[q*8];
    } else {
      const unsigned short* A = (const unsigned short*)Ap + (size_t)(gm0 + srow) * Kd + k0 + shalf;
      #pragma unroll
      for (int q = 0; q < 4; q++)
        *(uint4*)&As[srow][shalf + q*8] = *(const uint4*)(A + q*8);
    }
    const unsigned short* B = BT + (size_t)(gn0 + srow) * Kd + k0 + shalf;
    #pragma unroll
    for (int q = 0; q < 4; q++)
      *(uint4*)&Bs[srow][shalf + q*8] = *(const uint4*)(B + q*8);
    __syncthreads();
    #pragma unroll
    for (int kk = 0; kk < 64; kk += 32) {
      const int kof = kk + ((lane >> 4) << 3);
      bfv8 a[4], b[4];
      #pragma unroll
      for (int mf = 0; mf < 4; mf++)
        a[mf] = *(const bfv8*)&As[wm*64 + mf*16 + (lane & 15)][kof];
      #pragma unroll
      for (int nf = 0; nf < 4; nf++)
        b[nf] = *(const bfv8*)&Bs[wn*64 + nf*16 + (lane & 15)][kof];
      #pragma unroll
      for (int mf = 0; mf < 4; mf++)
        #pragma unroll
        for (int nf = 0; nf < 4; nf++)
          acc[mf][nf] = mfma16(a[mf], b[nf], acc[mf][nf]);
    }
    __syncthreads();
  }

  // epilogue — C/D layout: col = lane&15, row = (lane>>4)*4 + reg  [HW-verified]
  #pragma unroll
  for (int mf = 0; mf < 4; mf++) {
    #pragma unroll
    for (int nf = 0; nf < 4; nf++) {
      int col = gn0 + wn*64 + nf*16 + (lane & 15);
      float bc = bias[col];
      #pragma unroll
      for (int r = 0; r < 4; r++) {
        int row = gm0 + wm*64 + mf*16 + ((lane >> 4) << 2) + r;
        float v = acc[mf][nf][r] + bc;
        if (EPI == 0) {
          obf[(size_t)row * N + col] = f2bf(geluf(v));
        } else {
          integ[(size_t)row * DDIM + col] += halt[row] * v * iw[col];
        }
      }
    }
  }
}

// -------- router second stage: logits -> top-2 indices + renorm weights ------
__global__ __launch_bounds__(256) void router_k(
    const unsigned short* __restrict__ h1, const float* __restrict__ w_r2,
    const float* __restrict__ b_r2, int* __restrict__ topi, float* __restrict__ topw)
{
  int t = blockIdx.x * 4 + (threadIdx.x >> 6);
  int lane = threadIdx.x & 63;
  const unsigned short* hp = h1 + (size_t)t * 256 + lane * 4;
  float hv[4];
  #pragma unroll
  for (int j = 0; j < 4; j++) hv[j] = bf2f(hp[j]);
  float acc[8];
  #pragma unroll
  for (int e = 0; e < 8; e++) acc[e] = 0.f;
  #pragma unroll
  for (int j = 0; j < 4; j++) {
    const float* wr = w_r2 + (size_t)(lane*4 + j) * 8;
    #pragma unroll
    for (int e = 0; e < 8; e++) acc[e] += hv[j] * wr[e];
  }
  #pragma unroll
  for (int off = 32; off > 0; off >>= 1)
    #pragma unroll
    for (int e = 0; e < 8; e++) acc[e] += __shfl_xor(acc[e], off);
  if (lane == 0) {
    float lg[8];
    #pragma unroll
    for (int e = 0; e < 8; e++) lg[e] = acc[e] + b_r2[e];
    int i0 = 0; float m0 = lg[0];
    #pragma unroll
    for (int e = 1; e < 8; e++) if (lg[e] > m0) { m0 = lg[e]; i0 = e; }
    int i1 = -1; float m1 = -3.4e38f;
    #pragma unroll
    for (int e = 0; e < 8; e++) if (e != i0 && lg[e] > m1) { m1 = lg[e]; i1 = e; }
    // renormalized top-2 softmax weights: w0 = e^m0/(e^m0+e^m1)
    float w0 = 1.0f / (1.0f + expf(m1 - m0));
    topi[t*2] = i0; topi[t*2+1] = i1;
    topw[t*2] = w0; topw[t*2+1] = 1.0f - w0;
  }
}

// -------- halt gate second stage: sigmoid(h1 @ w_h2 + b_h2) ------------------
__global__ __launch_bounds__(256) void haltgate_k(
    const unsigned short* __restrict__ h1, const float* __restrict__ w_h2,
    const float* __restrict__ b_h2, float* __restrict__ halt)
{
  int t = blockIdx.x * 4 + (threadIdx.x >> 6);
  int lane = threadIdx.x & 63;
  const unsigned short* hp = h1 + (size_t)t * 256 + lane * 4;
  float s = 0.f;
  #pragma unroll
  for (int j = 0; j < 4; j++) s += bf2f(hp[j]) * w_h2[lane*4 + j];
  #pragma unroll
  for (int off = 32; off > 0; off >>= 1) s += __shfl_xor(s, off);
  if (lane == 0) halt[t] = sigmf(s + b_h2[0]);
}

// -------- expert bucketing ---------------------------------------------------
__global__ __launch_bounds__(256) void bucket_k(
    const int* __restrict__ topi, int* __restrict__ cnt, int* __restrict__ slots)
{
  int g = blockIdx.x * 256 + threadIdx.x;   // slot id = t*2 + k
  int e = topi[g];
  int p = atomicAdd(&cnt[e], 1);
  slots[e * 32768 + p] = g;
}

__global__ void desc_k(const int* __restrict__ cnt, int* __restrict__ desc,
                       int* __restrict__ ndesc)
{
  if (threadIdx.x == 0 && blockIdx.x == 0) {
    int nt = 0;
    for (int e = 0; e < NEXP; e++) {
      int c = cnt[e];
      for (int o = 0; o < c; o += 64) {
        int rem = c - o;
        desc[nt*3+0] = e; desc[nt*3+1] = o; desc[nt*3+2] = rem < 64 ? rem : 64;
        nt++;
      }
    }
    ndesc[0] = nt;
  }
}

// -------- fused expert kernel (shared: ROUTED=false; routed: true) -----------
// phase1: hid[64][64] = gelu(ctx_tile @ w1 + b1), K=2048 (ctx = [integ | v])
// phase2: per 64-wide d-chunk compute alpha/beta/gate columns and _inl combine
template<bool ROUTED>
__global__ __launch_bounds__(256) void expert_k(
    const float* __restrict__ integ, const float* __restrict__ vcur,
    const unsigned short* __restrict__ w1T_s, const float* __restrict__ b1_s,
    const unsigned short* __restrict__ w2T_s, const float* __restrict__ b2_s,
    const float* __restrict__ swp, const float* __restrict__ mu,
    float* __restrict__ x_acc, float* __restrict__ v_acc,
    const int* __restrict__ desc, const int* __restrict__ ndesc,
    const int* __restrict__ slots, const float* __restrict__ topw,
    const unsigned short* __restrict__ ew1T, const float* __restrict__ eb1,
    const unsigned short* __restrict__ ew2T, const float* __restrict__ eb2)
{
  __shared__ unsigned short As[64][72];
  __shared__ unsigned short Bs[64][72];
  __shared__ unsigned short Hs[64][72];
  __shared__ unsigned short W2s[192][72];
  __shared__ int s_slot[64];

  const int tid = threadIdx.x, lane = tid & 63, w = tid >> 6;
  int cnt = 64, tbase = blockIdx.x * 64;
  const unsigned short *w1T, *w2T;
  const float *b1, *b2;
  if (ROUTED) {
    if (blockIdx.x >= ndesc[0]) return;
    int e    = desc[blockIdx.x*3+0];
    int eoff = desc[blockIdx.x*3+1];
    cnt      = desc[blockIdx.x*3+2];
    w1T = ew1T + (size_t)e * 64 * 2048;  b1 = eb1 + e * 64;
    w2T = ew2T + (size_t)e * 3072 * 64;  b2 = eb2 + e * 3072;
    if (tid < 64) s_slot[tid] = (tid < cnt) ? slots[e * 32768 + eoff + tid] : -1;
  } else {
    w1T = w1T_s; b1 = b1_s; w2T = w2T_s; b2 = b2_s;
  }
  __syncthreads();
  const float sw = sigmf(swp[0]);

  // ---- phase 1: hidden = gelu(ctx @ w1 + b1), wave w owns rows w*16..w*16+15
  f32x4 hacc[4];
  #pragma unroll
  for (int i = 0; i < 4; i++) hacc[i] = f32x4{0.f,0.f,0.f,0.f};
  const int ar = tid >> 2, ac = (tid & 3) * 16;   // staging: 4 threads/row
  for (int k0 = 0; k0 < 2048; k0 += 64) {
    // stage A (ctx tile, f32 -> bf16); k<1024 from integ, else from v
    int tok; bool valid = true;
    if (ROUTED) { int s = s_slot[ar]; valid = (s >= 0); tok = valid ? (s >> 1) : 0; }
    else tok = tbase + ar;
    unsigned short tmp[16];
    if (valid) {
      const float* src = (k0 < 1024 ? integ : vcur) + (size_t)tok * DDIM + (k0 & 1023) + ac;
      #pragma unroll
      for (int q = 0; q < 4; q++) {
        float4 f = *(const float4*)(src + q * 4);
        tmp[q*4+0] = f2bf(f.x); tmp[q*4+1] = f2bf(f.y);
        tmp[q*4+2] = f2bf(f.z); tmp[q*4+3] = f2bf(f.w);
      }
    } else {
      #pragma unroll
      for (int q = 0; q < 16; q++) tmp[q] = 0;
    }
    *(uint4*)&As[ar][ac]     = *(uint4*)&tmp[0];
    *(uint4*)&As[ar][ac + 8] = *(uint4*)&tmp[8];
    // stage B (w1T rows = hidden cols, K-contiguous)
    const unsigned short* bsrc = w1T + (size_t)ar * 2048 + k0 + ac;
    *(uint4*)&Bs[ar][ac]     = *(const uint4*)(bsrc);
    *(uint4*)&Bs[ar][ac + 8] = *(const uint4*)(bsrc + 8);
    __syncthreads();
    #pragma unroll
    for (int kk = 0; kk < 64; kk += 32) {
      const int kof = kk + ((lane >> 4) << 3);
      bfv8 a = *(const bfv8*)&As[w*16 + (lane & 15)][kof];
      #pragma unroll
      for (int cf = 0; cf < 4; cf++) {
        bfv8 b = *(const bfv8*)&Bs[cf*16 + (lane & 15)][kof];
        hacc[cf] = mfma16(a, b, hacc[cf]);
      }
    }
    __syncthreads();
  }
  // bias + gelu -> Hs (bf16)
  #pragma unroll
  for (int cf = 0; cf < 4; cf++) {
    int col = cf*16 + (lane & 15);
    float bb = b1[col];
    #pragma unroll
    for (int r = 0; r < 4; r++) {
      int row = w*16 + ((lane >> 4) << 2) + r;
      Hs[row][col] = f2bf(geluf(hacc[cf][r] + bb));
    }
  }
  __syncthreads();

  // ---- phase 2: ctrl chunks + _inl epilogue, 64 d-columns at a time
  for (int d0 = 0; d0 < 1024; d0 += 64) {
    #pragma unroll
    for (int j = 0; j < 6; j++) {
      int s = tid + j * 256;               // 1536 16B segments
      int row = s >> 3, sg = (s & 7) * 8;
      int grow = row < 64 ? d0 + row
               : row < 128 ? 1024 + d0 + (row - 64)
                           : 2048 + d0 + (row - 128);
      *(uint4*)&W2s[row][sg] = *(const uint4*)&w2T[(size_t)grow * 64 + sg];
    }
    __syncthreads();
    f32x4 cacc[3][4];
    #pragma unroll
    for (int c = 0; c < 3; c++)
      #pragma unroll
      for (int cf = 0; cf < 4; cf++)
        cacc[c][cf] = f32x4{0.f,0.f,0.f,0.f};
    #pragma unroll
    for (int kk = 0; kk < 64; kk += 32) {
      const int kof = kk + ((lane >> 4) << 3);
      bfv8 a = *(const bfv8*)&Hs[w*16 + (lane & 15)][kof];
      #pragma unroll
      for (int c = 0; c < 3; c++)
        #pragma unroll
        for (int cf = 0; cf < 4; cf++) {
          bfv8 b = *(const bfv8*)&W2s[c*64 + cf*16 + (lane & 15)][kof];
          cacc[c][cf] = mfma16(a, b, cacc[c][cf]);
        }
    }
    #pragma unroll
    for (int cf = 0; cf < 4; cf++) {
      int d = d0 + cf*16 + (lane & 15);
      float ba = b2[d], bbv = b2[1024 + d], bg = b2[2048 + d];
      float muv = mu[d];
      #pragma unroll
      for (int r = 0; r < 4; r++) {
        int rl = w*16 + ((lane >> 4) << 2) + r;
        int tok; float cw;
        if (ROUTED) {
          if (rl >= cnt) continue;
          int s = s_slot[rl]; tok = s >> 1; cw = (1.0f - sw) * topw[s];
        } else { tok = tbase + rl; cw = sw; }
        float al = sigmf(cacc[0][cf][r] + ba);
        float be = softpf(cacc[1][cf][r] + bbv);
        float ga = sigmf(cacc[2][cf][r] + bg);
        size_t ix = (size_t)tok * DDIM + d;
        float xx = integ[ix], vv = vcur[ix];
        float err = xx - muv;
        float vn = al * vv - be * err;
        float xn = xx + DTC * ga * vn;
        if (ROUTED) {
          unsafeAtomicAdd(&x_acc[ix], cw * xn);
          unsafeAtomicAdd(&v_acc[ix], cw * vn);
        } else {
          x_acc[ix] = cw * xn;
          v_acc[ix] = cw * vn;
        }
      }
    }
    __syncthreads();
  }
}

// -----------------------------------------------------------------------------
extern "C" void kernel_launch(void* const* d_in, const int* in_sizes, int n_in,
                              void* d_out, int out_size, void* d_ws, size_t ws_size,
                              hipStream_t stream)
{
  const float* x    = (const float*)d_in[0];
  const float* w_r1 = (const float*)d_in[1];
  const float* b_r1 = (const float*)d_in[2];
  const float* w_r2 = (const float*)d_in[3];
  const float* b_r2 = (const float*)d_in[4];
  const float* w_h1 = (const float*)d_in[5];
  const float* b_h1 = (const float*)d_in[6];
  const float* w_h2 = (const float*)d_in[7];
  const float* b_h2 = (const float*)d_in[8];
  const float* ew1  = (const float*)d_in[9];
  const float* eb1  = (const float*)d_in[10];
  const float* ew2  = (const float*)d_in[11];
  const float* eb2  = (const float*)d_in[12];
  const float* w_s1 = (const float*)d_in[13];
  const float* b_s1 = (const float*)d_in[14];
  const float* w_s2 = (const float*)d_in[15];
  const float* b_s2 = (const float*)d_in[16];
  const float* swt  = (const float*)d_in[17];
  const float* w_f1 = (const float*)d_in[18];
  const float* b_f1 = (const float*)d_in[19];
  const float* w_f2 = (const float*)d_in[20];
  const float* b_f2 = (const float*)d_in[21];
  const float* iw   = (const float*)d_in[22];
  const float* mu   = (const float*)d_in[23];
  float* out = (float*)d_out;        // doubles as `integrated`

  char* ws = (char*)d_ws;
  size_t off = 0;
  auto take = [&](size_t bytes) -> char* {
    char* p = ws + off;
    off = (off + bytes + 255) & ~(size_t)255;
    return p;
  };
  const size_t TD4 = (size_t)TOK * DDIM * 4;
  float* x_acc = (float*)take(TD4);
  float* vb0   = (float*)take(TD4);
  float* vb1   = (float*)take(TD4);
  unsigned short* h1 = (unsigned short*)take((size_t)TOK * 256 * 2);
  float* halt = (float*)take((size_t)TOK * 4);
  int*   topi = (int*)take((size_t)TOK * 2 * 4);
  float* topw = (float*)take((size_t)TOK * 2 * 4);
  int*   cnt  = (int*)take(64);
  int*   ndsc = (int*)take(64);
  int*   desc = (int*)take(520 * 3 * 4);
  int*   slots= (int*)take((size_t)NEXP * 32768 * 4);
  unsigned short* w_r1T = (unsigned short*)take((size_t)256 * 1024 * 2);
  unsigned short* w_h1T = (unsigned short*)take((size_t)256 * 1024 * 2);
  unsigned short* w_f1T = (unsigned short*)take((size_t)2048 * 1024 * 2);
  unsigned short* w_f2T = (unsigned short*)take((size_t)1024 * 2048 * 2);
  unsigned short* w_s1T = (unsigned short*)take((size_t)64 * 2048 * 2);
  unsigned short* w_s2T = (unsigned short*)take((size_t)3072 * 64 * 2);
  unsigned short* ew1T  = (unsigned short*)take((size_t)NEXP * 64 * 2048 * 2);
  unsigned short* ew2T  = (unsigned short*)take((size_t)NEXP * 3072 * 64 * 2);
  if (off > ws_size) return;   // needs ~227 MB

  hipMemcpyAsync(out, x, TD4, hipMemcpyDeviceToDevice, stream);   // integrated = x
  hipMemsetAsync(vb0, 0, TD4, stream);                            // v = 0
  hipMemsetAsync(cnt, 0, 64, stream);

  dim3 tb(32, 8);
  transpose_cast<<<dim3(  8, 32, 1), tb, 0, stream>>>(w_r1, w_r1T, 1024,  256);
  transpose_cast<<<dim3(  8, 32, 1), tb, 0, stream>>>(w_h1, w_h1T, 1024,  256);
  transpose_cast<<<dim3( 64, 32, 1), tb, 0, stream>>>(w_f1, w_f1T, 1024, 2048);
  transpose_cast<<<dim3( 32, 64, 1), tb, 0, stream>>>(w_f2, w_f2T, 2048, 1024);
  transpose_cast<<<dim3(  2, 64, 1), tb, 0, stream>>>(w_s1, w_s1T, 2048,   64);
  transpose_cast<<<dim3( 96,  2, 1), tb, 0, stream>>>(w_s2, w_s2T,   64, 3072);
  transpose_cast<<<dim3(  2, 64, 8), tb, 0, stream>>>(ew1,  ew1T,  2048,   64);
  transpose_cast<<<dim3( 96,  2, 8), tb, 0, stream>>>(ew2,  ew2T,    64, 3072);

  // router (runs once; h1 buffer reused by halt gate later)
  gemm_k<0, true><<<dim3(2, 128), 256, 0, stream>>>(
      x, w_r1T, b_r1, 1024, 256, h1, nullptr, nullptr, nullptr);
  router_k<<<TOK / 4, 256, 0, stream>>>(h1, w_r2, b_r2, topi, topw);
  bucket_k<<<TOK * 2 / 256, 256, 0, stream>>>(topi, cnt, slots);
  desc_k<<<1, 64, 0, stream>>>(cnt, desc, ndsc);

  float* vcur = vb0;
  float* vacc = vb1;
  for (int it = 0; it < 2; it++) {
    // shared expert: full non-atomic write of x_acc/v_acc = sw * (x_sh, v_sh)
    expert_k<false><<<TOK / 64, 256, 0, stream>>>(
        out, vcur, w_s1T, b_s1, w_s2T, b_s2, swt, mu, x_acc, vacc,
        nullptr, nullptr, nullptr, nullptr, nullptr, nullptr, nullptr, nullptr);
    // routed experts: atomic accumulate (1-sw)*wt * (x_r, v_r)
    expert_k<true><<<520, 256, 0, stream>>>(
        out, vcur, nullptr, nullptr, nullptr, nullptr, swt, mu, x_acc, vacc,
        desc, ndsc, slots, topw, ew1T, eb1, ew2T, eb2);
    // halt gate
    gemm_k<0, true><<<dim3(2, 128), 256, 0, stream>>>(
        x_acc, w_h1T, b_h1, 1024, 256, h1, nullptr, nullptr, nullptr);
    haltgate_k<<<TOK / 4, 256, 0, stream>>>(h1, w_h2, b_h2, halt);
    // refine MLP; rh reuses the dead v buffer ([T,2048] bf16 == [T,1024] f32)
    unsigned short* rh = (unsigned short*)vcur;
    gemm_k<0, true><<<dim3(16, 128), 256, 0, stream>>>(
        x_acc, w_f1T, b_f1, 1024, 2048, rh, nullptr, nullptr, nullptr);
    gemm_k<1, false><<<dim3(8, 128), 256, 0, stream>>>(
        rh, w_f2T, b_f2, 2048, 1024, nullptr, halt, iw, out);
    // v <- v_next
    float* t2 = vcur; vcur = vacc; vacc = t2;
  }
}

// Round 2
// 2086.364 us; speedup vs baseline: 1.3832x; 1.3832x over previous
//
#include <hip/hip_runtime.h>

// FusedMoEIntegrator — MI355X/gfx950, round 1.
// Change vs round 0: expert path rebuilt as E1 (ctx build/zero) + E2 (phase-1
// GEMM, desc-grouped, global_load_lds + XOR-swizzled LDS) + E3 (phase-2 GEMM
// + _inl epilogue fused, atomics). gemm_k & router path unchanged.

#define TOK   16384
#define DDIM  1024
#define NEXP  8
#define DTC   0.1f
#define MAXDESC 512
#define NDBLK 392   // upper bound on desc entries (263 routed + 128 shared + pad)

using f32x4 = __attribute__((ext_vector_type(4))) float;
using bfv8  = __attribute__((ext_vector_type(8))) short;

__device__ __forceinline__ unsigned short f2bf(float x){
  unsigned u = __builtin_bit_cast(unsigned, x);
  u += 0x7fffu + ((u >> 16) & 1u);          // RNE (finite inputs only)
  return (unsigned short)(u >> 16);
}
__device__ __forceinline__ float bf2f(unsigned short h){
  return __builtin_bit_cast(float, ((unsigned)h) << 16);
}
__device__ __forceinline__ float geluf(float x){
  return 0.5f * x * (1.0f + erff(x * 0.7071067811865476f));   // exact gelu
}
__device__ __forceinline__ float sigmf(float x){ return 1.0f/(1.0f+__expf(-x)); }
__device__ __forceinline__ float softpf(float x){
  return fmaxf(x, 0.0f) + __logf(1.0f + __expf(-fabsf(x)));
}
__device__ __forceinline__ f32x4 mfma16(bfv8 a, bfv8 b, f32x4 c){
  return __builtin_amdgcn_mfma_f32_16x16x32_bf16(a, b, c, 0, 0, 0);
}
// async global->LDS, 16B per lane; LDS dest = wave-uniform base + lane*16
typedef __attribute__((address_space(1))) const void gvoid_t;
typedef __attribute__((address_space(3))) void svoid_t;
__device__ __forceinline__ void gload16(const void* g, void* l){
  __builtin_amdgcn_global_load_lds((gvoid_t*)g, (svoid_t*)l, 16, 0, 0);
}

// -------- transpose+cast: src f32 [R][C] (batch z) -> dst bf16 [C][R] --------
__global__ __launch_bounds__(256) void transpose_cast(
    const float* __restrict__ src, unsigned short* __restrict__ dst, int R, int C)
{
  __shared__ float tile[32][33];
  size_t bo = (size_t)blockIdx.z * R * C;
  const float* s = src + bo;
  unsigned short* d = dst + bo;
  int c0 = blockIdx.x * 32, r0 = blockIdx.y * 32;
  int tx = threadIdx.x, ty = threadIdx.y;
  #pragma unroll
  for (int j = 0; j < 4; j++)
    tile[ty + 8*j][tx] = s[(size_t)(r0 + ty + 8*j) * C + c0 + tx];
  __syncthreads();
  #pragma unroll
  for (int j = 0; j < 4; j++)
    d[(size_t)(c0 + ty + 8*j) * R + r0 + tx] = f2bf(tile[tx][ty + 8*j]);
}

// -------- main GEMM (unchanged from round 0) ---------------------------------
template<int EPI, bool AF32>
__global__ __launch_bounds__(256) void gemm_k(
    const void* __restrict__ Ap, const unsigned short* __restrict__ BT,
    const float* __restrict__ bias, int Kd, int N,
    unsigned short* __restrict__ obf,
    const float* __restrict__ halt, const float* __restrict__ iw,
    float* __restrict__ integ)
{
  __shared__ unsigned short As[128][72];
  __shared__ unsigned short Bs[128][72];
  const int tid  = threadIdx.x;
  const int lane = tid & 63;
  const int w    = tid >> 6;
  const int wm   = w >> 1, wn = w & 1;
  const int gm0  = blockIdx.y * 128, gn0 = blockIdx.x * 128;
  const int srow  = tid >> 1;
  const int shalf = (tid & 1) * 32;

  f32x4 acc[4][4];
  #pragma unroll
  for (int i = 0; i < 4; i++)
    #pragma unroll
    for (int j = 0; j < 4; j++)
      acc[i][j] = f32x4{0.f, 0.f, 0.f, 0.f};

  for (int k0 = 0; k0 < Kd; k0 += 64) {
    if (AF32) {
      const float* A = (const float*)Ap + (size_t)(gm0 + srow) * Kd + k0 + shalf;
      unsigned short tmp[32];
      #pragma unroll
      for (int q = 0; q < 8; q++) {
        float4 f = *(const float4*)(A + q * 4);
        tmp[q*4+0] = f2bf(f.x); tmp[q*4+1] = f2bf(f.y);
        tmp[q*4+2] = f2bf(f.z); tmp[q*4+3] = f2bf(f.w);
      }
      #pragma unroll
      for (int q = 0; q < 4; q++)
        *(uint4*)&As[srow][shalf + q*8] = *(uint4*)&tmp[q*8];
    } else {
      const unsigned short* A = (const unsigned short*)Ap + (size_t)(gm0 + srow) * Kd + k0 + shalf;
      #pragma unroll
      for (int q = 0; q < 4; q++)
        *(uint4*)&As[srow][shalf + q*8] = *(const uint4*)(A + q*8);
    }
    const unsigned short* B = BT + (size_t)(gn0 + srow) * Kd + k0 + shalf;
    #pragma unroll
    for (int q = 0; q < 4; q++)
      *(uint4*)&Bs[srow][shalf + q*8] = *(const uint4*)(B + q*8);
    __syncthreads();
    #pragma unroll
    for (int kk = 0; kk < 64; kk += 32) {
      const int kof = kk + ((lane >> 4) << 3);
      bfv8 a[4], b[4];
      #pragma unroll
      for (int mf = 0; mf < 4; mf++)
        a[mf] = *(const bfv8*)&As[wm*64 + mf*16 + (lane & 15)][kof];
      #pragma unroll
      for (int nf = 0; nf < 4; nf++)
        b[nf] = *(const bfv8*)&Bs[wn*64 + nf*16 + (lane & 15)][kof];
      #pragma unroll
      for (int mf = 0; mf < 4; mf++)
        #pragma unroll
        for (int nf = 0; nf < 4; nf++)
          acc[mf][nf] = mfma16(a[mf], b[nf], acc[mf][nf]);
    }
    __syncthreads();
  }

  #pragma unroll
  for (int mf = 0; mf < 4; mf++) {
    #pragma unroll
    for (int nf = 0; nf < 4; nf++) {
      int col = gn0 + wn*64 + nf*16 + (lane & 15);
      float bc = bias[col];
      #pragma unroll
      for (int r = 0; r < 4; r++) {
        int row = gm0 + wm*64 + mf*16 + ((lane >> 4) << 2) + r;
        float v = acc[mf][nf][r] + bc;
        if (EPI == 0) {
          obf[(size_t)row * N + col] = f2bf(geluf(v));
        } else {
          integ[(size_t)row * DDIM + col] += halt[row] * v * iw[col];
        }
      }
    }
  }
}

// -------- router second stage ------------------------------------------------
__global__ __launch_bounds__(256) void router_k(
    const unsigned short* __restrict__ h1, const float* __restrict__ w_r2,
    const float* __restrict__ b_r2, int* __restrict__ topi, float* __restrict__ topw)
{
  int t = blockIdx.x * 4 + (threadIdx.x >> 6);
  int lane = threadIdx.x & 63;
  const unsigned short* hp = h1 + (size_t)t * 256 + lane * 4;
  float hv[4];
  #pragma unroll
  for (int j = 0; j < 4; j++) hv[j] = bf2f(hp[j]);
  float acc[8];
  #pragma unroll
  for (int e = 0; e < 8; e++) acc[e] = 0.f;
  #pragma unroll
  for (int j = 0; j < 4; j++) {
    const float* wr = w_r2 + (size_t)(lane*4 + j) * 8;
    #pragma unroll
    for (int e = 0; e < 8; e++) acc[e] += hv[j] * wr[e];
  }
  #pragma unroll
  for (int off = 32; off > 0; off >>= 1)
    #pragma unroll
    for (int e = 0; e < 8; e++) acc[e] += __shfl_xor(acc[e], off);
  if (lane == 0) {
    float lg[8];
    #pragma unroll
    for (int e = 0; e < 8; e++) lg[e] = acc[e] + b_r2[e];
    int i0 = 0; float m0 = lg[0];
    #pragma unroll
    for (int e = 1; e < 8; e++) if (lg[e] > m0) { m0 = lg[e]; i0 = e; }
    int i1 = -1; float m1 = -3.4e38f;
    #pragma unroll
    for (int e = 0; e < 8; e++) if (e != i0 && lg[e] > m1) { m1 = lg[e]; i1 = e; }
    float w0 = 1.0f / (1.0f + expf(m1 - m0));
    topi[t*2] = i0; topi[t*2+1] = i1;
    topw[t*2] = w0; topw[t*2+1] = 1.0f - w0;
  }
}

// -------- halt gate second stage ----------------------------------------------
__global__ __launch_bounds__(256) void haltgate_k(
    const unsigned short* __restrict__ h1, const float* __restrict__ w_h2,
    const float* __restrict__ b_h2, float* __restrict__ halt)
{
  int t = blockIdx.x * 4 + (threadIdx.x >> 6);
  int lane = threadIdx.x & 63;
  const unsigned short* hp = h1 + (size_t)t * 256 + lane * 4;
  float s = 0.f;
  #pragma unroll
  for (int j = 0; j < 4; j++) s += bf2f(hp[j]) * w_h2[lane*4 + j];
  #pragma unroll
  for (int off = 32; off > 0; off >>= 1) s += __shfl_xor(s, off);
  if (lane == 0) halt[t] = sigmf(s + b_h2[0]);
}

// -------- expert bucketing ----------------------------------------------------
__global__ __launch_bounds__(256) void bucket_k(
    const int* __restrict__ topi, int* __restrict__ cnt, int* __restrict__ slots)
{
  int g = blockIdx.x * 256 + threadIdx.x;   // slot id = t*2 + k
  int e = topi[g];
  int p = atomicAdd(&cnt[e], 1);
  slots[e * 32768 + p] = g;
}

// desc entry: {e (8 = shared), goff, cnt, hbase}; 128-row tiles.
__global__ void desc_k(const int* __restrict__ cnt, int4* __restrict__ desc,
                       int* __restrict__ ndesc)
{
  if (threadIdx.x == 0 && blockIdx.x == 0) {
    int nt = 0, hb = 0;
    for (int e = 0; e <= 8; e++) {
      int c = (e < 8) ? cnt[e] : TOK;
      for (int o = 0; o < c; o += 128) {
        int rem = c - o; if (rem > 128) rem = 128;
        desc[nt] = make_int4(e, o, rem, hb);
        nt++; hb += 128;
      }
    }
    ndesc[0] = nt;
  }
}

// -------- E1: ctx build (bf16) + zero accumulators ----------------------------
// ctx[t][0:1024]=bf16(integ), [1024:2048]=bf16(v); then v:=0, xacc:=0.
__global__ __launch_bounds__(256) void ctx_k(
    const float* __restrict__ integ, float* __restrict__ vf,
    unsigned short* __restrict__ ctx, float* __restrict__ xacc)
{
  const int n = TOK * 256;   // float4-quads per array
  for (int i = blockIdx.x * 256 + threadIdx.x; i < n; i += gridDim.x * 256) {
    int t = i >> 8, c4 = (i & 255) * 4;
    float4 xi = ((const float4*)integ)[i];
    float4 vi = ((const float4*)vf)[i];
    ushort4 xb = {f2bf(xi.x), f2bf(xi.y), f2bf(xi.z), f2bf(xi.w)};
    ushort4 vb = {f2bf(vi.x), f2bf(vi.y), f2bf(vi.z), f2bf(vi.w)};
    *(ushort4*)&ctx[(size_t)t*2048 + c4]        = xb;
    *(ushort4*)&ctx[(size_t)t*2048 + 1024 + c4] = vb;
    ((float4*)vf)[i]   = float4{0.f,0.f,0.f,0.f};
    ((float4*)xacc)[i] = float4{0.f,0.f,0.f,0.f};
  }
}

// -------- E2: phase-1 GEMM  hidden[row][64] = gelu(ctx_row @ w1 + b1) ---------
// 128 rows per desc tile, K=2048, BK=64, global_load_lds + XOR seg swizzle.
__global__ __launch_bounds__(256) void exp1_k(
    const unsigned short* __restrict__ ctx,
    const int4* __restrict__ desc, const int* __restrict__ ndesc,
    const int* __restrict__ slots,
    const unsigned short* __restrict__ ew1T, const float* __restrict__ eb1,
    const unsigned short* __restrict__ ws1T, const float* __restrict__ bs1,
    unsigned short* __restrict__ hiddenG)
{
  __shared__ unsigned short As[128][64];
  __shared__ unsigned short Bs[64][64];
  __shared__ int s_tok[128];
  if (blockIdx.x >= ndesc[0]) return;
  int4 dd = desc[blockIdx.x];
  const int e = dd.x, goff = dd.y, cnt = dd.z, hbase = dd.w;
  const unsigned short* w1 = (e < 8) ? ew1T + (size_t)e * 64 * 2048 : ws1T;
  const float* b1 = (e < 8) ? eb1 + e * 64 : bs1;
  const int tid = threadIdx.x, lane = tid & 63, w = tid >> 6;

  if (tid < 128) {
    int tok;
    if (e < 8) tok = (tid < cnt) ? (slots[e * 32768 + goff + tid] >> 1) : 0;
    else       tok = goff + tid;
    s_tok[tid] = tok;
  }
  __syncthreads();

  const int arow = w*8 + (lane >> 3);               // row within 32-row group
  const int sseg = (lane & 7) ^ (lane >> 3);        // swizzled source segment
  const unsigned short* asrc[4];
  #pragma unroll
  for (int q = 0; q < 4; q++)
    asrc[q] = ctx + (size_t)s_tok[q*32 + arow] * 2048 + sseg * 8;
  const unsigned short* bsrc[2];
  #pragma unroll
  for (int q = 0; q < 2; q++)
    bsrc[q] = w1 + (size_t)(q*32 + arow) * 2048 + sseg * 8;

  f32x4 acc[2][4];
  #pragma unroll
  for (int i = 0; i < 2; i++)
    #pragma unroll
    for (int j = 0; j < 4; j++)
      acc[i][j] = f32x4{0.f,0.f,0.f,0.f};

  const int xr = (lane & 7) << 3;                   // read-side XOR (shorts)
  for (int k0 = 0; k0 < 2048; k0 += 64) {
    #pragma unroll
    for (int q = 0; q < 4; q++) gload16(asrc[q] + k0, &As[q*32 + w*8][0]);
    #pragma unroll
    for (int q = 0; q < 2; q++) gload16(bsrc[q] + k0, &Bs[q*32 + w*8][0]);
    __syncthreads();
    #pragma unroll
    for (int kk = 0; kk < 64; kk += 32) {
      const int kof = kk + ((lane >> 4) << 3);
      bfv8 a[2], b[4];
      #pragma unroll
      for (int mf = 0; mf < 2; mf++) {
        int r = w*32 + mf*16 + (lane & 15);
        a[mf] = *(const bfv8*)&As[r][kof ^ xr];
      }
      #pragma unroll
      for (int nf = 0; nf < 4; nf++) {
        int r = nf*16 + (lane & 15);
        b[nf] = *(const bfv8*)&Bs[r][kof ^ xr];
      }
      #pragma unroll
      for (int mf = 0; mf < 2; mf++)
        #pragma unroll
        for (int nf = 0; nf < 4; nf++)
          acc[mf][nf] = mfma16(a[mf], b[nf], acc[mf][nf]);
    }
    __syncthreads();
  }

  #pragma unroll
  for (int mf = 0; mf < 2; mf++) {
    #pragma unroll
    for (int nf = 0; nf < 4; nf++) {
      int col = nf*16 + (lane & 15);
      float bb = b1[col];
      #pragma unroll
      for (int r = 0; r < 4; r++) {
        int row = w*32 + mf*16 + ((lane >> 4) << 2) + r;
        hiddenG[(size_t)(hbase + row) * 64 + col] = f2bf(geluf(acc[mf][nf][r] + bb));
      }
    }
  }
}

// -------- E3: phase-2 GEMM + _inl epilogue (atomic combine) --------------------
// grid (NDBLK, 2): blockIdx.y splits d into halves of 512; 8 chunks of 64 d.
__global__ __launch_bounds__(256) void exp2_k(
    const unsigned short* __restrict__ hiddenG,
    const int4* __restrict__ desc, const int* __restrict__ ndesc,
    const int* __restrict__ slots, const float* __restrict__ topw,
    const unsigned short* __restrict__ ew2T, const float* __restrict__ eb2,
    const unsigned short* __restrict__ ws2T, const float* __restrict__ bs2,
    const float* __restrict__ swp, const float* __restrict__ mu,
    const unsigned short* __restrict__ ctx,
    float* __restrict__ xacc, float* __restrict__ vacc)
{
  __shared__ unsigned short Hs[128][64];
  __shared__ unsigned short W2s[192][64];
  __shared__ int   s_tok[128];
  __shared__ float s_cw[128];
  if (blockIdx.x >= ndesc[0]) return;
  int4 dd = desc[blockIdx.x];
  const int e = dd.x, goff = dd.y, cnt = dd.z, hbase = dd.w;
  const unsigned short* w2 = (e < 8) ? ew2T + (size_t)e * 3072 * 64 : ws2T;
  const float* b2 = (e < 8) ? eb2 + e * 3072 : bs2;
  const int tid = threadIdx.x, lane = tid & 63, w = tid >> 6;
  const float sw = sigmf(swp[0]);

  if (tid < 128) {
    int tok = 0; float cw = 0.f;
    if (e < 8) {
      if (tid < cnt) { int s = slots[e*32768 + goff + tid]; tok = s >> 1; cw = (1.f - sw) * topw[s]; }
    } else { tok = goff + tid; cw = sw; }
    s_tok[tid] = tok; s_cw[tid] = cw;
  }
  const int arow = w*8 + (lane >> 3);
  const int sseg = (lane & 7) ^ (lane >> 3);
  #pragma unroll
  for (int q = 0; q < 4; q++)
    gload16(hiddenG + (size_t)(hbase + q*32 + arow) * 64 + sseg*8, &Hs[q*32 + w*8][0]);
  __syncthreads();

  const int xr = (lane & 7) << 3;
  bfv8 afr[2][2];     // hidden A-fragments: constant across all d-chunks
  #pragma unroll
  for (int mf = 0; mf < 2; mf++)
    #pragma unroll
    for (int kk = 0; kk < 2; kk++) {
      int r = w*32 + mf*16 + (lane & 15);
      int kof = kk*32 + ((lane >> 4) << 3);
      afr[mf][kk] = *(const bfv8*)&Hs[r][kof ^ xr];
    }

  const int d0 = blockIdx.y * 512;
  for (int dc = 0; dc < 8; dc++) {
    const int d00 = d0 + dc * 64;
    #pragma unroll
    for (int q = 0; q < 6; q++) {
      int row  = q*32 + arow;                       // 0..191
      int grow = (row >> 6) * 1024 + d00 + (row & 63);
      gload16(w2 + (size_t)grow * 64 + sseg*8, &W2s[q*32 + w*8][0]);
    }
    __syncthreads();

    f32x4 acc[2][12];
    #pragma unroll
    for (int i = 0; i < 2; i++)
      #pragma unroll
      for (int j = 0; j < 12; j++)
        acc[i][j] = f32x4{0.f,0.f,0.f,0.f};
    #pragma unroll
    for (int kk = 0; kk < 2; kk++) {
      const int kof = kk*32 + ((lane >> 4) << 3);
      #pragma unroll
      for (int nf = 0; nf < 12; nf++) {
        int r = nf*16 + (lane & 15);
        bfv8 b = *(const bfv8*)&W2s[r][kof ^ xr];
        acc[0][nf] = mfma16(afr[0][kk], b, acc[0][nf]);
        acc[1][nf] = mfma16(afr[1][kk], b, acc[1][nf]);
      }
    }

    #pragma unroll
    for (int mf = 0; mf < 2; mf++) {
      #pragma unroll
      for (int cf = 0; cf < 4; cf++) {
        int d = d00 + cf*16 + (lane & 15);
        float ba = b2[d], bb = b2[1024 + d], bg = b2[2048 + d];
        float muv = mu[d];
        #pragma unroll
        for (int r = 0; r < 4; r++) {
          int row = w*32 + mf*16 + ((lane >> 4) << 2) + r;
          if (row >= cnt) continue;
          float cw = s_cw[row]; int tok = s_tok[row];
          float al = sigmf(acc[mf][cf][r] + ba);
          float be = softpf(acc[mf][4 + cf][r] + bb);
          float ga = sigmf(acc[mf][8 + cf][r] + bg);
          float xx = bf2f(ctx[(size_t)tok*2048 + d]);
          float vv = bf2f(ctx[(size_t)tok*2048 + 1024 + d]);
          float vn = al * vv - be * (xx - muv);
          float xn = xx + DTC * ga * vn;
          size_t ix = (size_t)tok * DDIM + d;
          unsafeAtomicAdd(&xacc[ix], cw * xn);
          unsafeAtomicAdd(&vacc[ix], cw * vn);
        }
      }
    }
    __syncthreads();
  }
}

// -----------------------------------------------------------------------------
extern "C" void kernel_launch(void* const* d_in, const int* in_sizes, int n_in,
                              void* d_out, int out_size, void* d_ws, size_t ws_size,
                              hipStream_t stream)
{
  const float* x    = (const float*)d_in[0];
  const float* w_r1 = (const float*)d_in[1];
  const float* b_r1 = (const float*)d_in[2];
  const float* w_r2 = (const float*)d_in[3];
  const float* b_r2 = (const float*)d_in[4];
  const float* w_h1 = (const float*)d_in[5];
  const float* b_h1 = (const float*)d_in[6];
  const float* w_h2 = (const float*)d_in[7];
  const float* b_h2 = (const float*)d_in[8];
  const float* ew1  = (const float*)d_in[9];
  const float* eb1  = (const float*)d_in[10];
  const float* ew2  = (const float*)d_in[11];
  const float* eb2  = (const float*)d_in[12];
  const float* w_s1 = (const float*)d_in[13];
  const float* b_s1 = (const float*)d_in[14];
  const float* w_s2 = (const float*)d_in[15];
  const float* b_s2 = (const float*)d_in[16];
  const float* swt  = (const float*)d_in[17];
  const float* w_f1 = (const float*)d_in[18];
  const float* b_f1 = (const float*)d_in[19];
  const float* w_f2 = (const float*)d_in[20];
  const float* b_f2 = (const float*)d_in[21];
  const float* iw   = (const float*)d_in[22];
  const float* mu   = (const float*)d_in[23];
  float* out = (float*)d_out;        // doubles as `integrated`

  char* ws = (char*)d_ws;
  size_t off = 0;
  auto take = [&](size_t bytes) -> char* {
    char* p = ws + off;
    off = (off + bytes + 255) & ~(size_t)255;
    return p;
  };
  const size_t TD4 = (size_t)TOK * DDIM * 4;
  float* xacc = (float*)take(TD4);
  float* vf   = (float*)take(TD4);
  unsigned short* ctx = (unsigned short*)take((size_t)TOK * 2048 * 2);  // also rh
  unsigned short* hiddenG = (unsigned short*)take((size_t)NDBLK * 128 * 64 * 2);
  unsigned short* h1 = (unsigned short*)take((size_t)TOK * 256 * 2);
  float* halt = (float*)take((size_t)TOK * 4);
  int*   topi = (int*)take((size_t)TOK * 2 * 4);
  float* topw = (float*)take((size_t)TOK * 2 * 4);
  int*   cnt  = (int*)take(64);
  int*   ndsc = (int*)take(64);
  int4*  desc = (int4*)take((size_t)MAXDESC * 16);
  int*   slots= (int*)take((size_t)NEXP * 32768 * 4);
  unsigned short* w_r1T = (unsigned short*)take((size_t)256 * 1024 * 2);
  unsigned short* w_h1T = (unsigned short*)take((size_t)256 * 1024 * 2);
  unsigned short* w_f1T = (unsigned short*)take((size_t)2048 * 1024 * 2);
  unsigned short* w_f2T = (unsigned short*)take((size_t)1024 * 2048 * 2);
  unsigned short* w_s1T = (unsigned short*)take((size_t)64 * 2048 * 2);
  unsigned short* w_s2T = (unsigned short*)take((size_t)3072 * 64 * 2);
  unsigned short* ew1T  = (unsigned short*)take((size_t)NEXP * 64 * 2048 * 2);
  unsigned short* ew2T  = (unsigned short*)take((size_t)NEXP * 3072 * 64 * 2);
  if (off > ws_size) return;   // needs ~223 MB

  hipMemcpyAsync(out, x, TD4, hipMemcpyDeviceToDevice, stream);   // integrated = x
  hipMemsetAsync(vf, 0, TD4, stream);                             // v = 0
  hipMemsetAsync(cnt, 0, 64, stream);

  dim3 tb(32, 8);
  transpose_cast<<<dim3(  8, 32, 1), tb, 0, stream>>>(w_r1, w_r1T, 1024,  256);
  transpose_cast<<<dim3(  8, 32, 1), tb, 0, stream>>>(w_h1, w_h1T, 1024,  256);
  transpose_cast<<<dim3( 64, 32, 1), tb, 0, stream>>>(w_f1, w_f1T, 1024, 2048);
  transpose_cast<<<dim3( 32, 64, 1), tb, 0, stream>>>(w_f2, w_f2T, 2048, 1024);
  transpose_cast<<<dim3(  2, 64, 1), tb, 0, stream>>>(w_s1, w_s1T, 2048,   64);
  transpose_cast<<<dim3( 96,  2, 1), tb, 0, stream>>>(w_s2, w_s2T,   64, 3072);
  transpose_cast<<<dim3(  2, 64, 8), tb, 0, stream>>>(ew1,  ew1T,  2048,   64);
  transpose_cast<<<dim3( 96,  2, 8), tb, 0, stream>>>(ew2,  ew2T,    64, 3072);

  // router (runs once)
  gemm_k<0, true><<<dim3(2, 128), 256, 0, stream>>>(
      x, w_r1T, b_r1, 1024, 256, h1, nullptr, nullptr, nullptr);
  router_k<<<TOK / 4, 256, 0, stream>>>(h1, w_r2, b_r2, topi, topw);
  bucket_k<<<TOK * 2 / 256, 256, 0, stream>>>(topi, cnt, slots);
  desc_k<<<1, 64, 0, stream>>>(cnt, desc, ndsc);

  for (int it = 0; it < 2; it++) {
    // E1: ctx = [bf16(out) | bf16(vf)]; vf := 0; xacc := 0
    ctx_k<<<2048, 256, 0, stream>>>(out, vf, ctx, xacc);
    // E2: hidden for all shared+routed rows
    exp1_k<<<NDBLK, 256, 0, stream>>>(ctx, desc, ndsc, slots,
                                      ew1T, eb1, w_s1T, b_s1, hiddenG);
    // E3: ctrl + _inl, atomic combine into xacc (=x_next) and vf (=v_next)
    exp2_k<<<dim3(NDBLK, 2), 256, 0, stream>>>(hiddenG, desc, ndsc, slots, topw,
                                               ew2T, eb2, w_s2T, b_s2, swt, mu,
                                               ctx, xacc, vf);
    // halt gate
    gemm_k<0, true><<<dim3(2, 128), 256, 0, stream>>>(
        xacc, w_h1T, b_h1, 1024, 256, h1, nullptr, nullptr, nullptr);
    haltgate_k<<<TOK / 4, 256, 0, stream>>>(h1, w_h2, b_h2, halt);
    // refine MLP; rh reuses ctx (dead until next E1)
    unsigned short* rh = ctx;
    gemm_k<0, true><<<dim3(16, 128), 256, 0, stream>>>(
        xacc, w_f1T, b_f1, 1024, 2048, rh, nullptr, nullptr, nullptr);
    gemm_k<1, false><<<dim3(8, 128), 256, 0, stream>>>(
        rh, w_f2T, b_f2, 2048, 1024, nullptr, halt, iw, out);
  }
}

// Round 3
// 1389.433 us; speedup vs baseline: 2.0770x; 1.5016x over previous
//
#include <hip/hip_runtime.h>

// FusedMoEIntegrator — MI355X/gfx950, round 2.
// Changes vs round 1:
//  - exp2 atomics removed: writes packed (bf16 w*v_n | bf16 w*g*v_n) per slot*d
//    to padPK (streaming); new combine_k gathers 3 slots/token -> x_next, v_next.
//  - x_next (xaccB) and v are bf16 everywhere downstream; f32 xacc/vf buffers gone.
//  - gemm_k rewritten: global_load_lds width-16 staging + XOR swizzle, bf16 A
//    (lda param), 0 bank conflicts, 32 MFMA/wave/K-step.
//  - d processed in two halves so padPK = 96 MB; total ws ~= 222 MB (round-1 size).

#define TOK   16384
#define DDIM  1024
#define NEXP  8
#define DTC   0.1f
#define MAXDESC 512
#define NDBLK 392

using f32x4 = __attribute__((ext_vector_type(4))) float;
using bfv8  = __attribute__((ext_vector_type(8))) short;

__device__ __forceinline__ unsigned short f2bf(float x){
  unsigned u = __builtin_bit_cast(unsigned, x);
  u += 0x7fffu + ((u >> 16) & 1u);
  return (unsigned short)(u >> 16);
}
__device__ __forceinline__ float bf2f(unsigned short h){
  return __builtin_bit_cast(float, ((unsigned)h) << 16);
}
__device__ __forceinline__ float geluf(float x){
  return 0.5f * x * (1.0f + erff(x * 0.7071067811865476f));
}
__device__ __forceinline__ float sigmf(float x){ return 1.0f/(1.0f+__expf(-x)); }
__device__ __forceinline__ float softpf(float x){
  return fmaxf(x, 0.0f) + __logf(1.0f + __expf(-fabsf(x)));
}
__device__ __forceinline__ f32x4 mfma16(bfv8 a, bfv8 b, f32x4 c){
  return __builtin_amdgcn_mfma_f32_16x16x32_bf16(a, b, c, 0, 0, 0);
}
typedef __attribute__((address_space(1))) const void gvoid_t;
typedef __attribute__((address_space(3))) void svoid_t;
__device__ __forceinline__ void gload16(const void* g, void* l){
  __builtin_amdgcn_global_load_lds((gvoid_t*)g, (svoid_t*)l, 16, 0, 0);
}

// -------- transpose+cast: src f32 [R][C] (batch z) -> dst bf16 [C][R] --------
__global__ __launch_bounds__(256) void transpose_cast(
    const float* __restrict__ src, unsigned short* __restrict__ dst, int R, int C)
{
  __shared__ float tile[32][33];
  size_t bo = (size_t)blockIdx.z * R * C;
  const float* s = src + bo;
  unsigned short* d = dst + bo;
  int c0 = blockIdx.x * 32, r0 = blockIdx.y * 32;
  int tx = threadIdx.x, ty = threadIdx.y;
  #pragma unroll
  for (int j = 0; j < 4; j++)
    tile[ty + 8*j][tx] = s[(size_t)(r0 + ty + 8*j) * C + c0 + tx];
  __syncthreads();
  #pragma unroll
  for (int j = 0; j < 4; j++)
    d[(size_t)(c0 + ty + 8*j) * R + r0 + tx] = f2bf(tile[tx][ty + 8*j]);
}

// -------- ctx build: x-half = bf16(out); INIT also zeroes v-half -------------
template<bool INIT>
__global__ __launch_bounds__(256) void ctx_k(
    const float* __restrict__ outf, unsigned short* __restrict__ ctx)
{
  const int n = TOK * 256;   // float4 quads
  for (int i = blockIdx.x * 256 + threadIdx.x; i < n; i += gridDim.x * 256) {
    int t = i >> 8, c4 = (i & 255) * 4;
    float4 xi = ((const float4*)outf)[i];
    ushort4 xb = {f2bf(xi.x), f2bf(xi.y), f2bf(xi.z), f2bf(xi.w)};
    *(ushort4*)&ctx[(size_t)t*2048 + c4] = xb;
    if (INIT)
      *(ushort4*)&ctx[(size_t)t*2048 + 1024 + c4] = ushort4{0,0,0,0};
  }
}

// -------- main GEMM: C[M,N] = A[M,K](bf16,lda) @ BT[N,K]^T -------------------
// 128x128 tile, BK=64, global_load_lds + XOR swizzle, 4 waves.
// EPI 0: obf = bf16(gelu(acc+bias));  EPI 1: integ += halt[row]*(acc+bias)*iw[col]
template<int EPI>
__global__ __launch_bounds__(256) void gemm_k(
    const unsigned short* __restrict__ A, int lda,
    const unsigned short* __restrict__ BT,
    const float* __restrict__ bias, int Kd, int N,
    unsigned short* __restrict__ obf,
    const float* __restrict__ halt, const float* __restrict__ iw,
    float* __restrict__ integ)
{
  __shared__ unsigned short As[128][64];
  __shared__ unsigned short Bs[128][64];
  const int tid  = threadIdx.x, lane = tid & 63, w = tid >> 6;
  const int wm   = w >> 1, wn = w & 1;
  const int gm0  = blockIdx.y * 128, gn0 = blockIdx.x * 128;
  const int r8   = lane >> 3;
  const int sseg = (lane & 7) ^ r8;           // source-side swizzled segment

  const unsigned short* aga[4];
  const unsigned short* bga[4];
  #pragma unroll
  for (int c = 0; c < 4; c++) {
    aga[c] = A  + (size_t)(gm0 + w*32 + c*8 + r8) * lda + sseg*8;
    bga[c] = BT + (size_t)(gn0 + w*32 + c*8 + r8) * Kd  + sseg*8;
  }

  f32x4 acc[4][4];
  #pragma unroll
  for (int i = 0; i < 4; i++)
    #pragma unroll
    for (int j = 0; j < 4; j++)
      acc[i][j] = f32x4{0.f,0.f,0.f,0.f};

  const int xr = (lane & 7) << 3;             // read-side XOR (shorts)
  for (int k0 = 0; k0 < Kd; k0 += 64) {
    #pragma unroll
    for (int c = 0; c < 4; c++) gload16(aga[c] + k0, &As[w*32 + c*8][0]);
    #pragma unroll
    for (int c = 0; c < 4; c++) gload16(bga[c] + k0, &Bs[w*32 + c*8][0]);
    __syncthreads();
    #pragma unroll
    for (int kk = 0; kk < 64; kk += 32) {
      const int kof = kk + ((lane >> 4) << 3);
      bfv8 a[4], b[4];
      #pragma unroll
      for (int mf = 0; mf < 4; mf++)
        a[mf] = *(const bfv8*)&As[wm*64 + mf*16 + (lane & 15)][kof ^ xr];
      #pragma unroll
      for (int nf = 0; nf < 4; nf++)
        b[nf] = *(const bfv8*)&Bs[wn*64 + nf*16 + (lane & 15)][kof ^ xr];
      #pragma unroll
      for (int mf = 0; mf < 4; mf++)
        #pragma unroll
        for (int nf = 0; nf < 4; nf++)
          acc[mf][nf] = mfma16(a[mf], b[nf], acc[mf][nf]);
    }
    __syncthreads();
  }

  #pragma unroll
  for (int mf = 0; mf < 4; mf++) {
    #pragma unroll
    for (int nf = 0; nf < 4; nf++) {
      int col = gn0 + wn*64 + nf*16 + (lane & 15);
      float bc = bias[col];
      #pragma unroll
      for (int r = 0; r < 4; r++) {
        int row = gm0 + wm*64 + mf*16 + ((lane >> 4) << 2) + r;
        float v = acc[mf][nf][r] + bc;
        if (EPI == 0) {
          obf[(size_t)row * N + col] = f2bf(geluf(v));
        } else {
          integ[(size_t)row * DDIM + col] += halt[row] * v * iw[col];
        }
      }
    }
  }
}

// -------- router second stage ------------------------------------------------
__global__ __launch_bounds__(256) void router_k(
    const unsigned short* __restrict__ h1, const float* __restrict__ w_r2,
    const float* __restrict__ b_r2, int* __restrict__ topi, float* __restrict__ topw)
{
  int t = blockIdx.x * 4 + (threadIdx.x >> 6);
  int lane = threadIdx.x & 63;
  const unsigned short* hp = h1 + (size_t)t * 256 + lane * 4;
  float hv[4];
  #pragma unroll
  for (int j = 0; j < 4; j++) hv[j] = bf2f(hp[j]);
  float acc[8];
  #pragma unroll
  for (int e = 0; e < 8; e++) acc[e] = 0.f;
  #pragma unroll
  for (int j = 0; j < 4; j++) {
    const float* wr = w_r2 + (size_t)(lane*4 + j) * 8;
    #pragma unroll
    for (int e = 0; e < 8; e++) acc[e] += hv[j] * wr[e];
  }
  #pragma unroll
  for (int off = 32; off > 0; off >>= 1)
    #pragma unroll
    for (int e = 0; e < 8; e++) acc[e] += __shfl_xor(acc[e], off);
  if (lane == 0) {
    float lg[8];
    #pragma unroll
    for (int e = 0; e < 8; e++) lg[e] = acc[e] + b_r2[e];
    int i0 = 0; float m0 = lg[0];
    #pragma unroll
    for (int e = 1; e < 8; e++) if (lg[e] > m0) { m0 = lg[e]; i0 = e; }
    int i1 = -1; float m1 = -3.4e38f;
    #pragma unroll
    for (int e = 0; e < 8; e++) if (e != i0 && lg[e] > m1) { m1 = lg[e]; i1 = e; }
    float w0 = 1.0f / (1.0f + expf(m1 - m0));
    topi[t*2] = i0; topi[t*2+1] = i1;
    topw[t*2] = w0; topw[t*2+1] = 1.0f - w0;
  }
}

// -------- halt gate second stage ---------------------------------------------
__global__ __launch_bounds__(256) void haltgate_k(
    const unsigned short* __restrict__ h1, const float* __restrict__ w_h2,
    const float* __restrict__ b_h2, float* __restrict__ halt)
{
  int t = blockIdx.x * 4 + (threadIdx.x >> 6);
  int lane = threadIdx.x & 63;
  const unsigned short* hp = h1 + (size_t)t * 256 + lane * 4;
  float s = 0.f;
  #pragma unroll
  for (int j = 0; j < 4; j++) s += bf2f(hp[j]) * w_h2[lane*4 + j];
  #pragma unroll
  for (int off = 32; off > 0; off >>= 1) s += __shfl_xor(s, off);
  if (lane == 0) halt[t] = sigmf(s + b_h2[0]);
}

// -------- expert bucketing ---------------------------------------------------
__global__ __launch_bounds__(256) void bucket_k(
    const int* __restrict__ topi, int* __restrict__ cnt, int* __restrict__ slots)
{
  int g = blockIdx.x * 256 + threadIdx.x;
  int e = topi[g];
  int p = atomicAdd(&cnt[e], 1);
  slots[e * 32768 + p] = g;
}

__global__ void desc_k(const int* __restrict__ cnt, int4* __restrict__ desc,
                       int* __restrict__ ndesc)
{
  if (threadIdx.x == 0 && blockIdx.x == 0) {
    int nt = 0, hb = 0;
    for (int e = 0; e <= 8; e++) {
      int c = (e < 8) ? cnt[e] : TOK;
      for (int o = 0; o < c; o += 128) {
        int rem = c - o; if (rem > 128) rem = 128;
        desc[nt] = make_int4(e, o, rem, hb);
        nt++; hb += 128;
      }
    }
    ndesc[0] = nt;
  }
}

// -------- E2: phase-1 GEMM  hidden[row][64] = gelu(ctx_row @ w1 + b1) --------
__global__ __launch_bounds__(256) void exp1_k(
    const unsigned short* __restrict__ ctx,
    const int4* __restrict__ desc, const int* __restrict__ ndesc,
    const int* __restrict__ slots,
    const unsigned short* __restrict__ ew1T, const float* __restrict__ eb1,
    const unsigned short* __restrict__ ws1T, const float* __restrict__ bs1,
    unsigned short* __restrict__ hiddenG)
{
  __shared__ unsigned short As[128][64];
  __shared__ unsigned short Bs[64][64];
  __shared__ int s_tok[128];
  if (blockIdx.x >= ndesc[0]) return;
  int4 dd = desc[blockIdx.x];
  const int e = dd.x, goff = dd.y, cnt = dd.z, hbase = dd.w;
  const unsigned short* w1 = (e < 8) ? ew1T + (size_t)e * 64 * 2048 : ws1T;
  const float* b1 = (e < 8) ? eb1 + e * 64 : bs1;
  const int tid = threadIdx.x, lane = tid & 63, w = tid >> 6;

  if (tid < 128) {
    int tok;
    if (e < 8) tok = (tid < cnt) ? (slots[e * 32768 + goff + tid] >> 1) : 0;
    else       tok = goff + tid;
    s_tok[tid] = tok;
  }
  __syncthreads();

  const int arow = w*8 + (lane >> 3);
  const int sseg = (lane & 7) ^ (lane >> 3);
  const unsigned short* asrc[4];
  #pragma unroll
  for (int q = 0; q < 4; q++)
    asrc[q] = ctx + (size_t)s_tok[q*32 + arow] * 2048 + sseg * 8;
  const unsigned short* bsrc[2];
  #pragma unroll
  for (int q = 0; q < 2; q++)
    bsrc[q] = w1 + (size_t)(q*32 + arow) * 2048 + sseg * 8;

  f32x4 acc[2][4];
  #pragma unroll
  for (int i = 0; i < 2; i++)
    #pragma unroll
    for (int j = 0; j < 4; j++)
      acc[i][j] = f32x4{0.f,0.f,0.f,0.f};

  const int xr = (lane & 7) << 3;
  for (int k0 = 0; k0 < 2048; k0 += 64) {
    #pragma unroll
    for (int q = 0; q < 4; q++) gload16(asrc[q] + k0, &As[q*32 + w*8][0]);
    #pragma unroll
    for (int q = 0; q < 2; q++) gload16(bsrc[q] + k0, &Bs[q*32 + w*8][0]);
    __syncthreads();
    #pragma unroll
    for (int kk = 0; kk < 64; kk += 32) {
      const int kof = kk + ((lane >> 4) << 3);
      bfv8 a[2], b[4];
      #pragma unroll
      for (int mf = 0; mf < 2; mf++)
        a[mf] = *(const bfv8*)&As[w*32 + mf*16 + (lane & 15)][kof ^ xr];
      #pragma unroll
      for (int nf = 0; nf < 4; nf++)
        b[nf] = *(const bfv8*)&Bs[nf*16 + (lane & 15)][kof ^ xr];
      #pragma unroll
      for (int mf = 0; mf < 2; mf++)
        #pragma unroll
        for (int nf = 0; nf < 4; nf++)
          acc[mf][nf] = mfma16(a[mf], b[nf], acc[mf][nf]);
    }
    __syncthreads();
  }

  #pragma unroll
  for (int mf = 0; mf < 2; mf++) {
    #pragma unroll
    for (int nf = 0; nf < 4; nf++) {
      int col = nf*16 + (lane & 15);
      float bb = b1[col];
      #pragma unroll
      for (int r = 0; r < 4; r++) {
        int row = w*32 + mf*16 + ((lane >> 4) << 2) + r;
        hiddenG[(size_t)(hbase + row) * 64 + col] = f2bf(geluf(acc[mf][nf][r] + bb));
      }
    }
  }
}

// -------- E3: phase-2 GEMM + per-slot packed store (no atomics) --------------
// padPK[sid][0:512) = (bf16(cw*v_n) | bf16(cw*g*v_n)<<16), sid routed=s, shared=32768+t
__global__ __launch_bounds__(256) void exp2_k(
    const unsigned short* __restrict__ hiddenG,
    const int4* __restrict__ desc, const int* __restrict__ ndesc,
    const int* __restrict__ slots, const float* __restrict__ topw,
    const unsigned short* __restrict__ ew2T, const float* __restrict__ eb2,
    const unsigned short* __restrict__ ws2T, const float* __restrict__ bs2,
    const float* __restrict__ swp, const float* __restrict__ mu,
    const unsigned short* __restrict__ ctx,
    unsigned* __restrict__ padPK, int dhalf)
{
  __shared__ unsigned short Hs[128][64];
  __shared__ unsigned short W2s[192][64];
  __shared__ int   s_tok[128];
  __shared__ int   s_sid[128];
  __shared__ float s_cw[128];
  if (blockIdx.x >= ndesc[0]) return;
  int4 dd = desc[blockIdx.x];
  const int e = dd.x, goff = dd.y, cnt = dd.z, hbase = dd.w;
  const unsigned short* w2 = (e < 8) ? ew2T + (size_t)e * 3072 * 64 : ws2T;
  const float* b2 = (e < 8) ? eb2 + e * 3072 : bs2;
  const int tid = threadIdx.x, lane = tid & 63, w = tid >> 6;
  const float sw = sigmf(swp[0]);

  if (tid < 128) {
    int tok = 0, sid = -1; float cw = 0.f;
    if (e < 8) {
      if (tid < cnt) { int s = slots[e*32768 + goff + tid]; tok = s >> 1; sid = s; cw = (1.f - sw) * topw[s]; }
    } else { tok = goff + tid; sid = 32768 + tok; cw = sw; }
    s_tok[tid] = tok; s_sid[tid] = sid; s_cw[tid] = cw;
  }
  const int arow = w*8 + (lane >> 3);
  const int sseg = (lane & 7) ^ (lane >> 3);
  #pragma unroll
  for (int q = 0; q < 4; q++)
    gload16(hiddenG + (size_t)(hbase + q*32 + arow) * 64 + sseg*8, &Hs[q*32 + w*8][0]);
  __syncthreads();

  const int xr = (lane & 7) << 3;
  bfv8 afr[2][2];
  #pragma unroll
  for (int mf = 0; mf < 2; mf++)
    #pragma unroll
    for (int kk = 0; kk < 2; kk++) {
      int r = w*32 + mf*16 + (lane & 15);
      int kof = kk*32 + ((lane >> 4) << 3);
      afr[mf][kk] = *(const bfv8*)&Hs[r][kof ^ xr];
    }

  for (int dc = 0; dc < 8; dc++) {
    const int d00 = dhalf * 512 + dc * 64;
    #pragma unroll
    for (int q = 0; q < 6; q++) {
      int row  = q*32 + arow;
      int grow = (row >> 6) * 1024 + d00 + (row & 63);
      gload16(w2 + (size_t)grow * 64 + sseg*8, &W2s[q*32 + w*8][0]);
    }
    __syncthreads();

    f32x4 acc[2][12];
    #pragma unroll
    for (int i = 0; i < 2; i++)
      #pragma unroll
      for (int j = 0; j < 12; j++)
        acc[i][j] = f32x4{0.f,0.f,0.f,0.f};
    #pragma unroll
    for (int kk = 0; kk < 2; kk++) {
      const int kof = kk*32 + ((lane >> 4) << 3);
      #pragma unroll
      for (int nf = 0; nf < 12; nf++) {
        bfv8 b = *(const bfv8*)&W2s[nf*16 + (lane & 15)][kof ^ xr];
        acc[0][nf] = mfma16(afr[0][kk], b, acc[0][nf]);
        acc[1][nf] = mfma16(afr[1][kk], b, acc[1][nf]);
      }
    }

    #pragma unroll
    for (int mf = 0; mf < 2; mf++) {
      #pragma unroll
      for (int cf = 0; cf < 4; cf++) {
        int d = d00 + cf*16 + (lane & 15);
        float ba = b2[d], bb = b2[1024 + d], bg = b2[2048 + d];
        float muv = mu[d];
        #pragma unroll
        for (int r = 0; r < 4; r++) {
          int row = w*32 + mf*16 + ((lane >> 4) << 2) + r;
          if (row >= cnt) continue;
          float cw = s_cw[row]; int tok = s_tok[row];
          float al = sigmf(acc[mf][cf][r] + ba);
          float be = softpf(acc[mf][4 + cf][r] + bb);
          float ga = sigmf(acc[mf][8 + cf][r] + bg);
          float xx = bf2f(ctx[(size_t)tok*2048 + d]);
          float vv = bf2f(ctx[(size_t)tok*2048 + 1024 + d]);
          float vn = al * vv - be * (xx - muv);
          unsigned pk = (unsigned)f2bf(cw * vn) | ((unsigned)f2bf(cw * ga * vn) << 16);
          padPK[(size_t)s_sid[row] * 512 + (d - dhalf*512)] = pk;
        }
      }
    }
    __syncthreads();
  }
}

// -------- combine: x_next/v_next from 3 slots per token ----------------------
__global__ __launch_bounds__(256) void combine_k(
    const unsigned* __restrict__ padPK, unsigned short* __restrict__ ctx,
    unsigned short* __restrict__ xaccB, int dhalf)
{
  const int n = TOK * 128;   // uint4 groups (4 d each) per half
  const uint4* p4 = (const uint4*)padPK;
  for (int i = blockIdx.x * 256 + threadIdx.x; i < n; i += gridDim.x * 256) {
    int t = i >> 7, j = i & 127;
    int gd = dhalf*512 + j*4;
    uint4 p0 = p4[(size_t)(2*t)       * 128 + j];
    uint4 p1 = p4[(size_t)(2*t + 1)   * 128 + j];
    uint4 ps = p4[(size_t)(32768 + t) * 128 + j];
    ushort4 xs = *(const ushort4*)&ctx[(size_t)t*2048 + gd];
    unsigned pc[4][3] = {{p0.x,p1.x,ps.x},{p0.y,p1.y,ps.y},{p0.z,p1.z,ps.z},{p0.w,p1.w,ps.w}};
    unsigned short xi[4] = {xs.x, xs.y, xs.z, xs.w};
    ushort4 xo, vo;
    unsigned short* xop = (unsigned short*)&xo;
    unsigned short* vop = (unsigned short*)&vo;
    #pragma unroll
    for (int k = 0; k < 4; k++) {
      float v  = bf2f((unsigned short)(pc[k][0] & 0xffff))
               + bf2f((unsigned short)(pc[k][1] & 0xffff))
               + bf2f((unsigned short)(pc[k][2] & 0xffff));
      float gv = bf2f((unsigned short)(pc[k][0] >> 16))
               + bf2f((unsigned short)(pc[k][1] >> 16))
               + bf2f((unsigned short)(pc[k][2] >> 16));
      float x = bf2f(xi[k]);
      xop[k] = f2bf(x + DTC * gv);
      vop[k] = f2bf(v);
    }
    *(ushort4*)&xaccB[(size_t)t*1024 + gd]      = xo;
    *(ushort4*)&ctx[(size_t)t*2048 + 1024 + gd] = vo;
  }
}

// -----------------------------------------------------------------------------
extern "C" void kernel_launch(void* const* d_in, const int* in_sizes, int n_in,
                              void* d_out, int out_size, void* d_ws, size_t ws_size,
                              hipStream_t stream)
{
  const float* x    = (const float*)d_in[0];
  const float* w_r1 = (const float*)d_in[1];
  const float* b_r1 = (const float*)d_in[2];
  const float* w_r2 = (const float*)d_in[3];
  const float* b_r2 = (const float*)d_in[4];
  const float* w_h1 = (const float*)d_in[5];
  const float* b_h1 = (const float*)d_in[6];
  const float* w_h2 = (const float*)d_in[7];
  const float* b_h2 = (const float*)d_in[8];
  const float* ew1  = (const float*)d_in[9];
  const float* eb1  = (const float*)d_in[10];
  const float* ew2  = (const float*)d_in[11];
  const float* eb2  = (const float*)d_in[12];
  const float* w_s1 = (const float*)d_in[13];
  const float* b_s1 = (const float*)d_in[14];
  const float* w_s2 = (const float*)d_in[15];
  const float* b_s2 = (const float*)d_in[16];
  const float* swt  = (const float*)d_in[17];
  const float* w_f1 = (const float*)d_in[18];
  const float* b_f1 = (const float*)d_in[19];
  const float* w_f2 = (const float*)d_in[20];
  const float* b_f2 = (const float*)d_in[21];
  const float* iw   = (const float*)d_in[22];
  const float* mu   = (const float*)d_in[23];
  float* out = (float*)d_out;        // doubles as `integrated`

  char* ws = (char*)d_ws;
  size_t off = 0;
  auto take = [&](size_t bytes) -> char* {
    char* p = ws + off;
    off = (off + bytes + 255) & ~(size_t)255;
    return p;
  };
  const size_t TD4 = (size_t)TOK * DDIM * 4;
  unsigned short* xaccB = (unsigned short*)take((size_t)TOK * 1024 * 2);
  unsigned short* ctx   = (unsigned short*)take((size_t)TOK * 2048 * 2);
  unsigned* padPK = (unsigned*)take((size_t)49152 * 512 * 4);   // rh aliases this
  unsigned short* rh = (unsigned short*)padPK;                  // [T][2048] bf16
  unsigned short* hiddenG = (unsigned short*)take((size_t)NDBLK * 128 * 64 * 2);
  unsigned short* h1 = (unsigned short*)take((size_t)TOK * 256 * 2);
  float* halt = (float*)take((size_t)TOK * 4);
  int*   topi = (int*)take((size_t)TOK * 2 * 4);
  float* topw = (float*)take((size_t)TOK * 2 * 4);
  int*   cnt  = (int*)take(64);
  int*   ndsc = (int*)take(64);
  int4*  desc = (int4*)take((size_t)MAXDESC * 16);
  int*   slots= (int*)take((size_t)NEXP * 32768 * 4);
  unsigned short* w_r1T = (unsigned short*)take((size_t)256 * 1024 * 2);
  unsigned short* w_h1T = (unsigned short*)take((size_t)256 * 1024 * 2);
  unsigned short* w_f1T = (unsigned short*)take((size_t)2048 * 1024 * 2);
  unsigned short* w_f2T = (unsigned short*)take((size_t)1024 * 2048 * 2);
  unsigned short* w_s1T = (unsigned short*)take((size_t)64 * 2048 * 2);
  unsigned short* w_s2T = (unsigned short*)take((size_t)3072 * 64 * 2);
  unsigned short* ew1T  = (unsigned short*)take((size_t)NEXP * 64 * 2048 * 2);
  unsigned short* ew2T  = (unsigned short*)take((size_t)NEXP * 3072 * 64 * 2);
  if (off > ws_size) return;   // ~222 MB

  hipMemcpyAsync(out, x, TD4, hipMemcpyDeviceToDevice, stream);
  hipMemsetAsync(cnt, 0, 64, stream);

  dim3 tb(32, 8);
  transpose_cast<<<dim3(  8, 32, 1), tb, 0, stream>>>(w_r1, w_r1T, 1024,  256);
  transpose_cast<<<dim3(  8, 32, 1), tb, 0, stream>>>(w_h1, w_h1T, 1024,  256);
  transpose_cast<<<dim3( 64, 32, 1), tb, 0, stream>>>(w_f1, w_f1T, 1024, 2048);
  transpose_cast<<<dim3( 32, 64, 1), tb, 0, stream>>>(w_f2, w_f2T, 2048, 1024);
  transpose_cast<<<dim3(  2, 64, 1), tb, 0, stream>>>(w_s1, w_s1T, 2048,   64);
  transpose_cast<<<dim3( 96,  2, 1), tb, 0, stream>>>(w_s2, w_s2T,   64, 3072);
  transpose_cast<<<dim3(  2, 64, 8), tb, 0, stream>>>(ew1,  ew1T,  2048,   64);
  transpose_cast<<<dim3( 96,  2, 8), tb, 0, stream>>>(ew2,  ew2T,    64, 3072);

  // ctx init (x-half = bf16(x), v-half = 0), then router
  ctx_k<true><<<2048, 256, 0, stream>>>(out, ctx);
  gemm_k<0><<<dim3(2, 128), 256, 0, stream>>>(
      ctx, 2048, w_r1T, b_r1, 1024, 256, h1, nullptr, nullptr, nullptr);
  router_k<<<TOK / 4, 256, 0, stream>>>(h1, w_r2, b_r2, topi, topw);
  bucket_k<<<TOK * 2 / 256, 256, 0, stream>>>(topi, cnt, slots);
  desc_k<<<1, 64, 0, stream>>>(cnt, desc, ndsc);

  for (int it = 0; it < 2; it++) {
    if (it > 0)
      ctx_k<false><<<2048, 256, 0, stream>>>(out, ctx);   // refresh x-half only
    exp1_k<<<NDBLK, 256, 0, stream>>>(ctx, desc, ndsc, slots,
                                      ew1T, eb1, w_s1T, b_s1, hiddenG);
    for (int h = 0; h < 2; h++) {
      exp2_k<<<NDBLK, 256, 0, stream>>>(hiddenG, desc, ndsc, slots, topw,
                                        ew2T, eb2, w_s2T, b_s2, swt, mu,
                                        ctx, padPK, h);
      combine_k<<<2048, 256, 0, stream>>>(padPK, ctx, xaccB, h);
    }
    // halt gate
    gemm_k<0><<<dim3(2, 128), 256, 0, stream>>>(
        xaccB, 1024, w_h1T, b_h1, 1024, 256, h1, nullptr, nullptr, nullptr);
    haltgate_k<<<TOK / 4, 256, 0, stream>>>(h1, w_h2, b_h2, halt);
    // refine MLP (rh aliases padPK, dead until next exp2)
    gemm_k<0><<<dim3(16, 128), 256, 0, stream>>>(
        xaccB, 1024, w_f1T, b_f1, 1024, 2048, rh, nullptr, nullptr, nullptr);
    gemm_k<1><<<dim3(8, 128), 256, 0, stream>>>(
        rh, 2048, w_f2T, b_f2, 2048, 1024, nullptr, halt, iw, out);
  }
}